// Round 1
// baseline (233.122 us; speedup 1.0000x reference)
//
#include <hip/hip_runtime.h>

// Problem constants (fixed by the reference).
#define HW_TOT (2048 * 2048)
#define KLAB 32   // pred instance labels
#define NLAB 16   // target labels

struct WS {
    double s2;    // sum pred_score^2
    double sp;    // sum cls_out
    double spt;   // sum cls_out where target>0
    double sbce;  // sum of selected clamped log terms
    unsigned int hist[NLAB * KLAB];
};

__global__ __launch_bounds__(256) void connect_main(
    const int4* __restrict__ pim, const float4* __restrict__ ps,
    const float4* __restrict__ co, const int4* __restrict__ tm,
    WS* __restrict__ ws, int nvec)
{
    __shared__ unsigned int lh[NLAB * KLAB];
    for (int i = threadIdx.x; i < NLAB * KLAB; i += blockDim.x) lh[i] = 0u;
    __syncthreads();

    float s2 = 0.f, sp = 0.f, spt = 0.f, sbce = 0.f;

    const int stride = gridDim.x * blockDim.x;
    for (int i = blockIdx.x * blockDim.x + threadIdx.x; i < nvec; i += stride) {
        int4   pv = pim[i];
        float4 sv = ps[i];
        float4 cv = co[i];
        int4   tv = tm[i];

        const int*   pl = (const int*)&pv;
        const int*   tl = (const int*)&tv;
        const float* sc = (const float*)&sv;
        const float* pp = (const float*)&cv;

#pragma unroll
        for (int j = 0; j < 4; ++j) {
            float s = sc[j];
            float p = pp[j];
            int   t = tl[j];
            int   k = pl[j];

            s2 += s * s;
            sp += p;
            bool tb = (t > 0);
            // t*log(p) + (1-t)*log1p(-p), t binary -> select argument, one log.
            float sel = tb ? p : (1.0f - p);
            float lg = fmaxf(logf(sel), -100.0f);
            sbce += lg;
            if (tb) spt += p;

            atomicAdd(&lh[t * KLAB + k], 1u);
        }
    }

    // Wave-level reduction of the four float partials (64 lanes).
#pragma unroll
    for (int off = 32; off > 0; off >>= 1) {
        s2   += __shfl_down(s2, off);
        sp   += __shfl_down(sp, off);
        spt  += __shfl_down(spt, off);
        sbce += __shfl_down(sbce, off);
    }
    if ((threadIdx.x & 63) == 0) {
        atomicAdd(&ws->s2,   (double)s2);
        atomicAdd(&ws->sp,   (double)sp);
        atomicAdd(&ws->spt,  (double)spt);
        atomicAdd(&ws->sbce, (double)sbce);
    }

    __syncthreads();  // all LDS histogram updates done
    for (int i = threadIdx.x; i < NLAB * KLAB; i += blockDim.x) {
        unsigned int v = lh[i];
        if (v) atomicAdd(&ws->hist[i], v);
    }
}

__global__ __launch_bounds__(512) void connect_finalize(
    const WS* __restrict__ ws, float* __restrict__ out)
{
    __shared__ float fh[NLAB * KLAB];
    __shared__ float rowmin[NLAB];
    __shared__ float strow[NLAB];

    int tid = threadIdx.x;  // 512 threads: one per (n,k) pair
    fh[tid] = (float)ws->hist[tid];
    __syncthreads();

    int n = tid >> 5;
    int k = tid & 31;

    float st = 0.f, sp = 0.f;
#pragma unroll
    for (int kk = 0; kk < KLAB; ++kk) st += fh[n * KLAB + kk];
#pragma unroll
    for (int nn = 0; nn < NLAB; ++nn) sp += fh[nn * KLAB + k];

    float I   = fh[n * KLAB + k];
    float uni = st + sp;
    float pair = 100.0f * (uni - 2.0f * I) / (float)HW_TOT
               + 1.0f - (2.0f * I + 1.0f) / (uni + 1.0f);

    // min over k (32 consecutive lanes; xor masks <32 stay in each half-wave)
    float v = pair;
#pragma unroll
    for (int off = 16; off > 0; off >>= 1) v = fminf(v, __shfl_xor(v, off));

    if (k == 0) { rowmin[n] = v; strow[n] = st; }
    __syncthreads();

    if (tid == 0) {
        double hw = (double)HW_TOT;
        double res = ws->s2 / hw;              // MSE(pred_score, 0)
        res += -(ws->sbce) / hw;               // BCE(cls_out, t)
        double sum_t = hw - (double)strow[0];  // count(target>0)
        res += 1.0 - (2.0 * ws->spt + 1.0) / (ws->sp + sum_t + 1.0);  // dice
        float pm = 0.f;
#pragma unroll
        for (int i = 0; i < NLAB; ++i) pm += rowmin[i];
        res += (double)pm;
        out[0] = (float)(res / (double)NLAB);
    }
}

extern "C" void kernel_launch(void* const* d_in, const int* in_sizes, int n_in,
                              void* d_out, int out_size, void* d_ws, size_t ws_size,
                              hipStream_t stream) {
    const int4*   pim = (const int4*)d_in[0];    // pred_instance_mask (int32)
    const float4* ps  = (const float4*)d_in[1];  // pred_score (f32)
    const float4* co  = (const float4*)d_in[2];  // cls_out (f32)
    const int4*   tm  = (const int4*)d_in[3];    // target_mask (int32)
    float* out = (float*)d_out;
    WS* ws = (WS*)d_ws;

    hipMemsetAsync(ws, 0, sizeof(WS), stream);

    const int nvec = HW_TOT / 4;  // 1,048,576 vec4 elements
    connect_main<<<1024, 256, 0, stream>>>(pim, ps, co, tm, ws, nvec);
    connect_finalize<<<1, 512, 0, stream>>>(ws, out);
}

// Round 2
// 28.719 us; speedup vs baseline: 8.1175x; 8.1175x over previous
//
#include <hip/hip_runtime.h>

#define HW_TOT (2048 * 2048)
#define KLAB 32
#define NLAB 16
#define NBIN (NLAB * KLAB)   // 512
#define NCHUNK 32            // second-stage reduction fan-in

// ws layout: float4 parts[B] | u32 hist1[B][512] | u32 hist2[32][512]

__global__ __launch_bounds__(256) void connect_k1(
    const int4* __restrict__ pim, const float4* __restrict__ ps,
    const float4* __restrict__ co, const int4* __restrict__ tm,
    float4* __restrict__ parts, unsigned int* __restrict__ hist1, int nvec)
{
    __shared__ unsigned int lh[NBIN];
    __shared__ float red[4][4];  // [wave][s2,sp,spt,sbce]

    for (int i = threadIdx.x; i < NBIN; i += 256) lh[i] = 0u;
    __syncthreads();

    float s2 = 0.f, sp = 0.f, spt = 0.f, sbce = 0.f;

    const int stride = gridDim.x * blockDim.x;
    for (int i = blockIdx.x * blockDim.x + threadIdx.x; i < nvec; i += stride) {
        int4   pv = pim[i];
        float4 sv = ps[i];
        float4 cv = co[i];
        int4   tv = tm[i];

        const int*   pl = (const int*)&pv;
        const int*   tl = (const int*)&tv;
        const float* sc = (const float*)&sv;
        const float* pp = (const float*)&cv;

#pragma unroll
        for (int j = 0; j < 4; ++j) {
            float s = sc[j];
            float p = pp[j];
            int   t = tl[j];
            int   k = pl[j];

            s2 += s * s;
            sp += p;
            bool tb = (t > 0);
            float sel = tb ? p : (1.0f - p);
            float lg = fmaxf(__logf(sel), -100.0f);
            sbce += lg;
            if (tb) spt += p;

            atomicAdd(&lh[t * KLAB + k], 1u);
        }
    }

    // wave-level reduce (64 lanes)
#pragma unroll
    for (int off = 32; off > 0; off >>= 1) {
        s2   += __shfl_down(s2, off);
        sp   += __shfl_down(sp, off);
        spt  += __shfl_down(spt, off);
        sbce += __shfl_down(sbce, off);
    }
    int wave = threadIdx.x >> 6;
    if ((threadIdx.x & 63) == 0) {
        red[wave][0] = s2; red[wave][1] = sp; red[wave][2] = spt; red[wave][3] = sbce;
    }
    __syncthreads();  // red written AND all LDS histogram atomics complete

    if (threadIdx.x == 0) {
        float4 r;
        r.x = red[0][0] + red[1][0] + red[2][0] + red[3][0];
        r.y = red[0][1] + red[1][1] + red[2][1] + red[3][1];
        r.z = red[0][2] + red[1][2] + red[2][2] + red[3][2];
        r.w = red[0][3] + red[1][3] + red[2][3] + red[3][3];
        parts[blockIdx.x] = r;
    }
    // flush per-block histogram: pure coalesced stores, no atomics
    for (int i = threadIdx.x; i < NBIN; i += 256)
        hist1[(size_t)blockIdx.x * NBIN + i] = lh[i];
}

__global__ __launch_bounds__(256) void connect_k2(
    const unsigned int* __restrict__ hist1, unsigned int* __restrict__ hist2, int B)
{
    int tid   = blockIdx.x * 256 + threadIdx.x;  // 0..16383
    int bin   = tid & (NBIN - 1);
    int chunk = tid >> 9;                        // 0..31
    unsigned int s = 0u;
    for (int b = chunk; b < B; b += NCHUNK)
        s += hist1[(size_t)b * NBIN + bin];
    hist2[chunk * NBIN + bin] = s;
}

__global__ __launch_bounds__(512) void connect_k3(
    const unsigned int* __restrict__ hist2, const float4* __restrict__ parts,
    int B, float* __restrict__ out)
{
    __shared__ float  fh[NBIN];
    __shared__ double sred[8][4];
    __shared__ float  rowmin[NLAB];
    __shared__ float  strow[NLAB];

    int tid = threadIdx.x;  // 512 threads, one per (n,k) bin

    unsigned int h = 0u;
#pragma unroll
    for (int c = 0; c < NCHUNK; ++c) h += hist2[c * NBIN + tid];
    fh[tid] = (float)h;

    double s2 = 0.0, sp = 0.0, spt = 0.0, sbce = 0.0;
    for (int b = tid; b < B; b += 512) {
        float4 r = parts[b];
        s2 += r.x; sp += r.y; spt += r.z; sbce += r.w;
    }
#pragma unroll
    for (int off = 32; off > 0; off >>= 1) {
        s2   += __shfl_down(s2, off);
        sp   += __shfl_down(sp, off);
        spt  += __shfl_down(spt, off);
        sbce += __shfl_down(sbce, off);
    }
    if ((tid & 63) == 0) {
        int w = tid >> 6;
        sred[w][0] = s2; sred[w][1] = sp; sred[w][2] = spt; sred[w][3] = sbce;
    }
    __syncthreads();

    int n = tid >> 5;
    int k = tid & 31;

    float st = 0.f, spk = 0.f;
#pragma unroll
    for (int kk = 0; kk < KLAB; ++kk) st += fh[n * KLAB + kk];
#pragma unroll
    for (int nn = 0; nn < NLAB; ++nn) spk += fh[nn * KLAB + k];

    float I   = fh[n * KLAB + k];
    float uni = st + spk;
    float pair = 100.0f * (uni - 2.0f * I) / (float)HW_TOT
               + 1.0f - (2.0f * I + 1.0f) / (uni + 1.0f);

    float v = pair;
#pragma unroll
    for (int off = 16; off > 0; off >>= 1) v = fminf(v, __shfl_xor(v, off));

    if (k == 0) { rowmin[n] = v; strow[n] = st; }
    __syncthreads();

    if (tid == 0) {
        double S2 = 0, SP = 0, SPT = 0, SBCE = 0;
#pragma unroll
        for (int w = 0; w < 8; ++w) {
            S2 += sred[w][0]; SP += sred[w][1]; SPT += sred[w][2]; SBCE += sred[w][3];
        }
        double hw = (double)HW_TOT;
        double res = S2 / hw;                 // MSE(pred_score, 0)
        res += -SBCE / hw;                    // BCE(cls_out, t)
        double sum_t = hw - (double)strow[0]; // count(target > 0)
        res += 1.0 - (2.0 * SPT + 1.0) / (SP + sum_t + 1.0);
        float pm = 0.f;
#pragma unroll
        for (int i = 0; i < NLAB; ++i) pm += rowmin[i];
        res += (double)pm;
        out[0] = (float)(res / (double)NLAB);
    }
}

extern "C" void kernel_launch(void* const* d_in, const int* in_sizes, int n_in,
                              void* d_out, int out_size, void* d_ws, size_t ws_size,
                              hipStream_t stream) {
    const int4*   pim = (const int4*)d_in[0];
    const float4* ps  = (const float4*)d_in[1];
    const float4* co  = (const float4*)d_in[2];
    const int4*   tm  = (const int4*)d_in[3];
    float* out = (float*)d_out;

    int B = 1024;
    while ((size_t)B * (16 + 2048) + NCHUNK * NBIN * 4 > ws_size && B > 32) B >>= 1;

    char* base = (char*)d_ws;
    float4*       parts = (float4*)base;
    unsigned int* hist1 = (unsigned int*)(base + (size_t)B * 16);
    unsigned int* hist2 = (unsigned int*)(base + (size_t)B * 16 + (size_t)B * NBIN * 4);

    const int nvec = HW_TOT / 4;
    connect_k1<<<B, 256, 0, stream>>>(pim, ps, co, tm, parts, hist1, nvec);
    connect_k2<<<(NCHUNK * NBIN) / 256, 256, 0, stream>>>(hist1, hist2, B);
    connect_k3<<<1, 512, 0, stream>>>(hist2, parts, B, out);
}

// Round 4
// 23.658 us; speedup vs baseline: 9.8537x; 1.2139x over previous
//
#include <hip/hip_runtime.h>

#define HW_TOT (2048 * 2048)
#define KLAB 32
#define NLAB 16
#define NBIN (NLAB * KLAB)   // 512
#define NREP 32              // replicated global histograms
#define NBLK 1024            // k1 grid

typedef int   vint4   __attribute__((ext_vector_type(4)));
typedef float vfloat4 __attribute__((ext_vector_type(4)));

// ws layout: u32 hist2[NREP][NBIN] (64 KB, zeroed per call) | float4 parts[NBLK]

__global__ __launch_bounds__(256) void connect_k1(
    const vint4* __restrict__ pim, const vfloat4* __restrict__ ps,
    const vfloat4* __restrict__ co, const vint4* __restrict__ tm,
    float4* __restrict__ parts, unsigned int* __restrict__ hist2, int nvec)
{
    __shared__ unsigned int lh[NBIN];
    __shared__ float red[4][4];

    for (int i = threadIdx.x; i < NBIN; i += 256) lh[i] = 0u;
    __syncthreads();

    float s2 = 0.f, sp = 0.f, spt = 0.f, sbce = 0.f;

    const int stride = gridDim.x * blockDim.x;
    for (int i = blockIdx.x * blockDim.x + threadIdx.x; i < nvec; i += stride) {
        vint4   pv = __builtin_nontemporal_load(&pim[i]);
        vfloat4 sv = __builtin_nontemporal_load(&ps[i]);
        vfloat4 cv = __builtin_nontemporal_load(&co[i]);
        vint4   tv = __builtin_nontemporal_load(&tm[i]);

#pragma unroll
        for (int j = 0; j < 4; ++j) {
            float s = sv[j];
            float p = cv[j];
            int   t = tv[j];
            int   k = pv[j];

            s2 += s * s;
            sp += p;
            bool tb = (t > 0);
            float sel = tb ? p : (1.0f - p);
            float lg = fmaxf(__logf(sel), -100.0f);
            sbce += lg;
            if (tb) spt += p;

            atomicAdd(&lh[t * KLAB + k], 1u);
        }
    }

    // wave-level reduce of scalar partials (64 lanes)
#pragma unroll
    for (int off = 32; off > 0; off >>= 1) {
        s2   += __shfl_down(s2, off);
        sp   += __shfl_down(sp, off);
        spt  += __shfl_down(spt, off);
        sbce += __shfl_down(sbce, off);
    }
    int wave = threadIdx.x >> 6;
    if ((threadIdx.x & 63) == 0) {
        red[wave][0] = s2; red[wave][1] = sp; red[wave][2] = spt; red[wave][3] = sbce;
    }
    __syncthreads();  // red written AND all LDS histogram atomics complete

    if (threadIdx.x == 0) {
        float4 r;
        r.x = red[0][0] + red[1][0] + red[2][0] + red[3][0];
        r.y = red[0][1] + red[1][1] + red[2][1] + red[3][1];
        r.z = red[0][2] + red[1][2] + red[2][2] + red[3][2];
        r.w = red[0][3] + red[1][3] + red[2][3] + red[3][3];
        parts[blockIdx.x] = r;
    }

    // flush LDS histogram into one of NREP replicas: ~32 adds/address device-wide
    unsigned int* rep = hist2 + (blockIdx.x & (NREP - 1)) * NBIN;
    for (int i = threadIdx.x; i < NBIN; i += 256) {
        unsigned int v = lh[i];
        if (v) atomicAdd(&rep[i], v);
    }
}

__global__ __launch_bounds__(512) void connect_fin(
    const unsigned int* __restrict__ hist2, const float4* __restrict__ parts,
    int B, float* __restrict__ out)
{
    __shared__ float  fh[NBIN];
    __shared__ double sred[8][4];
    __shared__ float  rowmin[NLAB];
    __shared__ float  strow[NLAB];

    int tid = threadIdx.x;  // one thread per (n,k) bin

    unsigned int h = 0u;
#pragma unroll
    for (int c = 0; c < NREP; ++c) h += hist2[c * NBIN + tid];
    fh[tid] = (float)h;

    double s2 = 0.0, sp = 0.0, spt = 0.0, sbce = 0.0;
    for (int b = tid; b < B; b += 512) {
        float4 r = parts[b];
        s2 += r.x; sp += r.y; spt += r.z; sbce += r.w;
    }
#pragma unroll
    for (int off = 32; off > 0; off >>= 1) {
        s2   += __shfl_down(s2, off);
        sp   += __shfl_down(sp, off);
        spt  += __shfl_down(spt, off);
        sbce += __shfl_down(sbce, off);
    }
    if ((tid & 63) == 0) {
        int w = tid >> 6;
        sred[w][0] = s2; sred[w][1] = sp; sred[w][2] = spt; sred[w][3] = sbce;
    }
    __syncthreads();

    int n = tid >> 5;
    int k = tid & 31;

    float st = 0.f, spk = 0.f;
#pragma unroll
    for (int kk = 0; kk < KLAB; ++kk) st += fh[n * KLAB + kk];
#pragma unroll
    for (int nn = 0; nn < NLAB; ++nn) spk += fh[nn * KLAB + k];

    float I   = fh[n * KLAB + k];
    float uni = st + spk;
    float pair = 100.0f * (uni - 2.0f * I) / (float)HW_TOT
               + 1.0f - (2.0f * I + 1.0f) / (uni + 1.0f);

    float v = pair;
#pragma unroll
    for (int off = 16; off > 0; off >>= 1) v = fminf(v, __shfl_xor(v, off));

    if (k == 0) { rowmin[n] = v; strow[n] = st; }
    __syncthreads();

    if (tid == 0) {
        double S2 = 0, SP = 0, SPT = 0, SBCE = 0;
#pragma unroll
        for (int w = 0; w < 8; ++w) {
            S2 += sred[w][0]; SP += sred[w][1]; SPT += sred[w][2]; SBCE += sred[w][3];
        }
        double hw = (double)HW_TOT;
        double res = S2 / hw;                 // MSE(pred_score, 0)
        res += -SBCE / hw;                    // BCE(cls_out, t)
        double sum_t = hw - (double)strow[0]; // count(target > 0)
        res += 1.0 - (2.0 * SPT + 1.0) / (SP + sum_t + 1.0);
        float pm = 0.f;
#pragma unroll
        for (int i = 0; i < NLAB; ++i) pm += rowmin[i];
        res += (double)pm;
        out[0] = (float)(res / (double)NLAB);
    }
}

extern "C" void kernel_launch(void* const* d_in, const int* in_sizes, int n_in,
                              void* d_out, int out_size, void* d_ws, size_t ws_size,
                              hipStream_t stream) {
    const vint4*   pim = (const vint4*)d_in[0];
    const vfloat4* ps  = (const vfloat4*)d_in[1];
    const vfloat4* co  = (const vfloat4*)d_in[2];
    const vint4*   tm  = (const vint4*)d_in[3];
    float* out = (float*)d_out;

    unsigned int* hist2 = (unsigned int*)d_ws;
    float4*       parts = (float4*)((char*)d_ws + (size_t)NREP * NBIN * 4);

    (void)hipMemsetAsync(hist2, 0, (size_t)NREP * NBIN * 4, stream);

    const int nvec = HW_TOT / 4;
    connect_k1<<<NBLK, 256, 0, stream>>>(pim, ps, co, tm, parts, hist2, nvec);
    connect_fin<<<1, 512, 0, stream>>>(hist2, parts, NBLK, out);
}